// Round 8
// baseline (175.580 us; speedup 1.0000x reference)
//
#include <hip/hip_runtime.h>
#include <hip/hip_bf16.h>
#include <stdint.h>
#include <stddef.h>

// B=2, S=2048, D=1024, H=16, C=64
typedef __bf16 bf16;
typedef __bf16 bf16x4 __attribute__((ext_vector_type(4)));
typedef __bf16 bf16x8 __attribute__((ext_vector_type(8)));
typedef float f32x4 __attribute__((ext_vector_type(4)));

#define DEV __device__ __forceinline__

// async global->LDS, 16B per lane; LDS dest is wave-uniform base + lane*16
DEV void async16(const bf16* g, bf16* l) {
    __builtin_amdgcn_global_load_lds(
        (const __attribute__((address_space(1))) void*)g,
        (__attribute__((address_space(3))) void*)l,
        16, 0, 0);
}

// pack two f32 -> two bf16 (truncation) in ONE v_perm_b32.
// Truncation bias cancels in P/l since l is computed from the same packed P.
DEV uint32_t pktrunc(float lo, float hi) {
    return __builtin_amdgcn_perm(__builtin_bit_cast(uint32_t, hi),
                                 __builtin_bit_cast(uint32_t, lo), 0x07060302u);
}

// ---------------- prep: x->bf16 convert (z=4) + 4 weight transposes (z=0..3) --

__global__ void prep(const float* __restrict__ x,
                     const float* __restrict__ Wq, const float* __restrict__ Wk,
                     const float* __restrict__ Wv, const float* __restrict__ Wo,
                     bf16* __restrict__ xb, bf16* __restrict__ WqkvT,
                     bf16* __restrict__ WoT) {
    __shared__ float t[32][33];
    if (blockIdx.z == 4) {
        const int bid = blockIdx.y * 32 + blockIdx.x;
#pragma unroll
        for (int i = 0; i < 4; ++i) {
            const int idx = ((bid * 4 + i) * 256 + threadIdx.x) * 4;
            const float4 v = *(const float4*)(x + idx);
            bf16 o4[4] = {(bf16)v.x, (bf16)v.y, (bf16)v.z, (bf16)v.w};
            *(uint2*)(xb + idx) = *(const uint2*)o4;
        }
        return;
    }
    const float* src;
    bf16* dst;
    float scale = 1.0f;
    switch (blockIdx.z) {
        case 0: src = Wq; dst = WqkvT; scale = 0.125f * 1.4426950408889634f; break;
        case 1: src = Wk; dst = WqkvT + 1024 * 1024; break;
        case 2: src = Wv; dst = WqkvT + 2 * 1024 * 1024; break;
        default: src = Wo; dst = WoT; break;
    }
    const int c0 = blockIdx.x * 32, r0 = blockIdx.y * 32;
    const int tx = threadIdx.x & 31, ty = threadIdx.x >> 5;  // 32x8
#pragma unroll
    for (int i = 0; i < 32; i += 8)
        t[ty + i][tx] = src[(size_t)(r0 + ty + i) * 1024 + c0 + tx];
    __syncthreads();
#pragma unroll
    for (int i = 0; i < 32; i += 8)
        dst[(size_t)(c0 + ty + i) * 1024 + r0 + tx] = (bf16)(t[tx][ty + i] * scale);
}

// ---------------- GEMM (TM=4): C[m][n] = sum_k A[m][k] * BT[n][k] ----------
// 128x128 tile, BK=64 as two BK=32 panels. If VTout != nullptr, tiles with
// n0 >= 2048 are stored TRANSPOSED to VTout[n-2048][m] (bf16) instead of C.
// 1D grid + XCD-chunked swizzle: old dim3 grid had ncols%8==0 so XCD=col%8
// -> every XCD streamed ALL of A (8x A over-fetch, ~70MB). New: XCD owns an
// 8-row x 12-col tile rectangle (fetch ~40MB total; A panels L2-resident).

template <bool OUT_F32>
__global__ __launch_bounds__(256, 3) void gemm_bt(
    const bf16* __restrict__ A, const bf16* __restrict__ BT, void* __restrict__ Cout,
    int M, int N, int K, bf16* __restrict__ VTout) {
    __shared__ __attribute__((aligned(16))) bf16 As[2 * 128 * 32];
    __shared__ __attribute__((aligned(16))) bf16 Bs[2 * 128 * 32];
    const int tid = threadIdx.x;
    const int wid = tid >> 6;
    const int lane = tid & 63;
    const int quad = lane >> 4;
    const int l16 = lane & 15;
    const int wm = wid >> 1, wn = wid & 1;

    // XCD-rectangle swizzle: 768 blocks, XCD = orig%8 owns 8 rows x 12 cols
    const int orig = blockIdx.x;
    const int xcd = orig & 7, pos = orig >> 3;          // pos in [0,96)
    const int row = (xcd >> 1) * 8 + (pos & 7);         // [0,32)
    const int col = (xcd & 1) * 12 + (pos >> 3);        // [0,24)
    const int m0 = row * 128, n0 = col * 128;

    const int srow = wid * 32 + (lane >> 2);
    const int skcol = (lane & 3) * 8;
    const bf16* ag = A + (size_t)(m0 + srow) * K + skcol;
    const bf16* bg = BT + (size_t)(n0 + srow) * K + skcol;

    f32x4 acc[4][4];
#pragma unroll
    for (int i = 0; i < 4; ++i)
#pragma unroll
        for (int j = 0; j < 4; ++j) acc[i][j] = (f32x4){0.f, 0.f, 0.f, 0.f};

    for (int k0 = 0; k0 < K; k0 += 64) {
#pragma unroll
        for (int p = 0; p < 2; ++p) {
            async16(ag + k0 + p * 32, &As[p * 4096 + (wid * 32) * 32]);
            async16(ag + (size_t)16 * K + k0 + p * 32, &As[p * 4096 + (wid * 32 + 16) * 32]);
            async16(bg + k0 + p * 32, &Bs[p * 4096 + (wid * 32) * 32]);
            async16(bg + (size_t)16 * K + k0 + p * 32, &Bs[p * 4096 + (wid * 32 + 16) * 32]);
        }
        __syncthreads();

#pragma unroll
        for (int ks = 0; ks < 2; ++ks) {
            bf16x8 af[4], bfr[4];
#pragma unroll
            for (int mi = 0; mi < 4; ++mi)
                af[mi] = *(const bf16x8*)&As[ks * 4096 + (wm * 64 + mi * 16 + l16) * 32 + quad * 8];
#pragma unroll
            for (int ni = 0; ni < 4; ++ni)
                bfr[ni] = *(const bf16x8*)&Bs[ks * 4096 + (wn * 64 + ni * 16 + l16) * 32 + quad * 8];
#pragma unroll
            for (int mi = 0; mi < 4; ++mi)
#pragma unroll
                for (int ni = 0; ni < 4; ++ni)
                    acc[mi][ni] = __builtin_amdgcn_mfma_f32_16x16x32_bf16(
                        af[mi], bfr[ni], acc[mi][ni], 0, 0, 0);
        }
        __syncthreads();
    }

    if (VTout && n0 >= 2048) {
        // store transposed: VT[n-2048][m], pack 4 consecutive m (r) as 8B
#pragma unroll
        for (int mi = 0; mi < 4; ++mi)
#pragma unroll
            for (int ni = 0; ni < 4; ++ni) {
                bf16 pk[4] = {(bf16)acc[mi][ni][0], (bf16)acc[mi][ni][1],
                              (bf16)acc[mi][ni][2], (bf16)acc[mi][ni][3]};
                *(uint2*)&VTout[(size_t)(n0 - 2048 + wn * 64 + ni * 16 + l16) * 4096 +
                                (m0 + wm * 64 + mi * 16 + quad * 4)] = *(const uint2*)pk;
            }
        return;
    }
    if (OUT_F32) {
        float* C = (float*)Cout;
#pragma unroll
        for (int mi = 0; mi < 4; ++mi)
#pragma unroll
            for (int ni = 0; ni < 4; ++ni)
#pragma unroll
                for (int r = 0; r < 4; ++r)
                    C[(size_t)(m0 + wm * 64 + mi * 16 + quad * 4 + r) * N +
                      (n0 + wn * 64 + ni * 16 + l16)] = acc[mi][ni][r];
    } else {
        bf16* C = (bf16*)Cout;
#pragma unroll
        for (int mi = 0; mi < 4; ++mi)
#pragma unroll
            for (int ni = 0; ni < 4; ++ni)
#pragma unroll
                for (int r = 0; r < 4; ++r)
                    C[(size_t)(m0 + wm * 64 + mi * 16 + quad * 4 + r) * N +
                      (n0 + wn * 64 + ni * 16 + l16)] = (bf16)acc[mi][ni][r];
    }
}

// ---------------- GEMM (TM=2): 64x128 tile, fp32 out --------------------
// 1D grid + XCD swizzle: old mapping had XCD=col%8 (8 cols) -> each XCD
// read ALL of A (64MB total). New: XCD owns 16 rows x 4 cols (~24MB total).

__global__ __launch_bounds__(256, 4) void gemm_tm2(
    const bf16* __restrict__ A, const bf16* __restrict__ BT, float* __restrict__ C,
    int M, int N, int K) {
    __shared__ __attribute__((aligned(16))) bf16 As[2 * 64 * 32];
    __shared__ __attribute__((aligned(16))) bf16 Bs[2 * 128 * 32];
    const int tid = threadIdx.x;
    const int wid = tid >> 6;
    const int lane = tid & 63;
    const int quad = lane >> 4;
    const int l16 = lane & 15;
    const int wm = wid >> 1, wn = wid & 1;

    // 512 blocks: XCD = orig%8 owns 16 rows x 4 cols
    const int orig = blockIdx.x;
    const int xcd = orig & 7, pos = orig >> 3;          // pos in [0,64)
    const int row = (xcd >> 1) * 16 + (pos & 15);       // [0,64)
    const int col = (xcd & 1) * 4 + (pos >> 4);         // [0,8)
    const int m0 = row * 64, n0 = col * 128;

    const int srowA = wid * 16 + (lane >> 2);
    const int srowB = wid * 32 + (lane >> 2);
    const int skcol = (lane & 3) * 8;
    const bf16* ag = A + (size_t)(m0 + srowA) * K + skcol;
    const bf16* bg = BT + (size_t)(n0 + srowB) * K + skcol;

    f32x4 acc[2][4];
#pragma unroll
    for (int i = 0; i < 2; ++i)
#pragma unroll
        for (int j = 0; j < 4; ++j) acc[i][j] = (f32x4){0.f, 0.f, 0.f, 0.f};

    for (int k0 = 0; k0 < K; k0 += 64) {
#pragma unroll
        for (int p = 0; p < 2; ++p) {
            async16(ag + k0 + p * 32, &As[p * 2048 + (wid * 16) * 32]);
            async16(bg + k0 + p * 32, &Bs[p * 4096 + (wid * 32) * 32]);
            async16(bg + (size_t)16 * K + k0 + p * 32, &Bs[p * 4096 + (wid * 32 + 16) * 32]);
        }
        __syncthreads();

#pragma unroll
        for (int ks = 0; ks < 2; ++ks) {
            bf16x8 af[2], bfr[4];
#pragma unroll
            for (int mi = 0; mi < 2; ++mi)
                af[mi] = *(const bf16x8*)&As[ks * 2048 + (wm * 32 + mi * 16 + l16) * 32 + quad * 8];
#pragma unroll
            for (int ni = 0; ni < 4; ++ni)
                bfr[ni] = *(const bf16x8*)&Bs[ks * 4096 + (wn * 64 + ni * 16 + l16) * 32 + quad * 8];
#pragma unroll
            for (int mi = 0; mi < 2; ++mi)
#pragma unroll
                for (int ni = 0; ni < 4; ++ni)
                    acc[mi][ni] = __builtin_amdgcn_mfma_f32_16x16x32_bf16(
                        af[mi], bfr[ni], acc[mi][ni], 0, 0, 0);
        }
        __syncthreads();
    }

#pragma unroll
    for (int mi = 0; mi < 2; ++mi)
#pragma unroll
        for (int ni = 0; ni < 4; ++ni)
#pragma unroll
            for (int r = 0; r < 4; ++r)
                C[(size_t)(m0 + wm * 32 + mi * 16 + quad * 4 + r) * N +
                  (n0 + wn * 64 + ni * 16 + l16)] = acc[mi][ni][r];
}

// ---------------- flash attention (v16 = v11 EXACT + T5 setprio) ----------
// Structure ledger: v12 (Q=64 dbuf) 58.7, v13 (512thr lockstep) 48.7,
// v14 (V-from-L2) 135.6, v15 (K/V dbuf 1-barrier) 64.2 -- every deviation
// from v11's 2-barrier lockstep lost. v16 (v11 + setprio): 45.8 MEASURED
// twice (T5 confirmed). Do not restructure without a fully derived schedule.

__global__ __launch_bounds__(256, 2) void flash_attn(
    const bf16* __restrict__ QKV, const bf16* __restrict__ VT, bf16* __restrict__ att) {
    constexpr int LDK = 72;   // Ks stride: frag-read banks 4*(l16+quad) uniform
    constexpr int LDV = 136;  // Vs stride: b64 reads 2-way (free), writes 8-phase
    __shared__ __attribute__((aligned(16))) char smem[36864];
    bf16* Ks = (bf16*)smem;                // [128][72]  = 18432 B
    bf16* Vs = (bf16*)(smem + 18432);      // [64][136]  = 17408 B -> 35840
    float* Osc = (float*)smem;             // epilogue alias: 2 regions x 16 KB
    float* Lred = (float*)(smem + 32768);  // [4][64] floats

    const int tid = threadIdx.x, wid = tid >> 6, lane = tid & 63;
    const int quad = lane >> 4, l16 = lane & 15;
    const int qh = wid >> 1, kh = wid & 1;
    const int bh = blockIdx.x, qt = blockIdx.y;   // XCD = bh % 8 (L2-local K/V)
    const int b = bh >> 4, h = bh & 15;
    const int q0 = qt * 128;

    // ---- Q B-frags (resident): B[k=quad*8+j][n=l16] = Q[q][c] ----
    bf16x8 qf[4][2];
    {
        const bf16* qbase = QKV + (size_t)(b * 2048 + q0 + qh * 64 + l16) * 3072 + h * 64 + quad * 8;
#pragma unroll
        for (int mi = 0; mi < 4; ++mi)
#pragma unroll
            for (int ks = 0; ks < 2; ++ks)
                qf[mi][ks] = *(const bf16x8*)(qbase + (size_t)mi * 16 * 3072 + ks * 32);
    }

    // staging geometry (coalesced): K 128 rows x 128 B, V 64 rows x 256 B
    const int krow = tid >> 3, kcol = (tid & 7) * 8;   // 32 rows/pass, 4 passes
    const int vrow = tid >> 4, vcol = (tid & 15) * 8;  // 16 rows/pass, 4 passes
    const bf16* kg = QKV + (size_t)(b * 2048 + krow) * 3072 + 1024 + h * 64 + kcol;
    const bf16* vg = VT + (size_t)(h * 64 + vrow) * 4096 + b * 2048 + vcol;

    bf16x8 kr[4], vr[4];
#pragma unroll
    for (int p = 0; p < 4; ++p) {
        kr[p] = *(const bf16x8*)(kg + (size_t)(32 * p) * 3072);
        vr[p] = *(const bf16x8*)(vg + (size_t)(16 * p) * 4096);
    }

    const bf16 one = (bf16)1.0f;
    const bf16x8 onesf = (bf16x8){one, one, one, one, one, one, one, one};

    f32x4 o[4][4];
    f32x4 ls[4];
#pragma unroll
    for (int mi = 0; mi < 4; ++mi) {
        ls[mi] = (f32x4){0.f, 0.f, 0.f, 0.f};
#pragma unroll
        for (int ct = 0; ct < 4; ++ct) o[mi][ct] = (f32x4){0.f, 0.f, 0.f, 0.f};
    }

    for (int it = 0; it < 16; ++it) {
        // ---- stage prefetched regs -> LDS ----
#pragma unroll
        for (int p = 0; p < 4; ++p) {
            *(bf16x8*)&Ks[(32 * p + krow) * LDK + kcol] = kr[p];
            *(bf16x8*)&Vs[(16 * p + vrow) * LDV + vcol] = vr[p];
        }
        __syncthreads();

        // ---- prefetch next big-iter (hidden behind compute phase) ----
        if (it < 15) {
            const size_t ko = (size_t)(it + 1) * 128;
#pragma unroll
            for (int p = 0; p < 4; ++p) {
                kr[p] = *(const bf16x8*)(kg + (ko + 32 * p) * 3072);
                vr[p] = *(const bf16x8*)(vg + (size_t)(16 * p) * 4096 + ko);
            }
        }

        // ---- compute: wave's 64 keys as 2 pairs of 16-key groups ----
#pragma unroll
        for (int pr = 0; pr < 2; ++pr) {
            const int kb = kh * 64 + pr * 32;  // pair base (rel key)
            const bf16x8 kfA0 = *(const bf16x8*)&Ks[(kb + l16) * LDK + quad * 8];
            const bf16x8 kfA1 = *(const bf16x8*)&Ks[(kb + l16) * LDK + 32 + quad * 8];
            const bf16x8 kfB0 = *(const bf16x8*)&Ks[(kb + 16 + l16) * LDK + quad * 8];
            const bf16x8 kfB1 = *(const bf16x8*)&Ks[(kb + 16 + l16) * LDK + 32 + quad * 8];
            bf16x8 vf[4];
#pragma unroll
            for (int ct = 0; ct < 4; ++ct) {
                const bf16x4 lo = *(const bf16x4*)&Vs[(ct * 16 + l16) * LDV + kb + quad * 4];
                const bf16x4 hi = *(const bf16x4*)&Vs[(ct * 16 + l16) * LDV + kb + 16 + quad * 4];
                vf[ct] = (bf16x8){lo[0], lo[1], lo[2], lo[3], hi[0], hi[1], hi[2], hi[3]};
            }
            __builtin_amdgcn_s_setprio(1);
#pragma unroll
            for (int mi = 0; mi < 4; ++mi) {
                f32x4 sA = (f32x4){0.f, 0.f, 0.f, 0.f};
                f32x4 sB = (f32x4){0.f, 0.f, 0.f, 0.f};
                sA = __builtin_amdgcn_mfma_f32_16x16x32_bf16(kfA0, qf[mi][0], sA, 0, 0, 0);
                sA = __builtin_amdgcn_mfma_f32_16x16x32_bf16(kfA1, qf[mi][1], sA, 0, 0, 0);
                sB = __builtin_amdgcn_mfma_f32_16x16x32_bf16(kfB0, qf[mi][0], sB, 0, 0, 0);
                sB = __builtin_amdgcn_mfma_f32_16x16x32_bf16(kfB1, qf[mi][1], sB, 0, 0, 0);

                const float pa0 = __builtin_amdgcn_exp2f(sA[0]);
                const float pa1 = __builtin_amdgcn_exp2f(sA[1]);
                const float pa2 = __builtin_amdgcn_exp2f(sA[2]);
                const float pa3 = __builtin_amdgcn_exp2f(sA[3]);
                const float pb0 = __builtin_amdgcn_exp2f(sB[0]);
                const float pb1 = __builtin_amdgcn_exp2f(sB[1]);
                const float pb2 = __builtin_amdgcn_exp2f(sB[2]);
                const float pb3 = __builtin_amdgcn_exp2f(sB[3]);

                // P A-frag via truncation pack (4 v_perm); lane = P[q=l16][j0..7]
                union { uint32_t u[4]; bf16x8 v; } pu;
                pu.u[0] = pktrunc(pa0, pa1);
                pu.u[1] = pktrunc(pa2, pa3);
                pu.u[2] = pktrunc(pb0, pb1);
                pu.u[3] = pktrunc(pb2, pb3);
                const bf16x8 pf = pu.v;
#pragma unroll
                for (int ct = 0; ct < 4; ++ct)
                    o[mi][ct] = __builtin_amdgcn_mfma_f32_16x16x32_bf16(pf, vf[ct], o[mi][ct], 0, 0, 0);
                // l-sum on the matrix pipe: D[q][*] = sum_k pf (all cols equal)
                ls[mi] = __builtin_amdgcn_mfma_f32_16x16x32_bf16(pf, onesf, ls[mi], 0, 0, 0);
            }
            __builtin_amdgcn_s_setprio(0);
        }
        __syncthreads();
    }

    // ---- epilogue: publish l (already row-summed, q = mi*16+quad*4+r), ----
    // ---- cross-wave O reduce ----
    if (l16 == 0) {
#pragma unroll
        for (int mi = 0; mi < 4; ++mi)
#pragma unroll
            for (int r = 0; r < 4; ++r)
                Lred[wid * 64 + mi * 16 + quad * 4 + r] = ls[mi][r];
    }
    if (kh == 1) {
        float* dst = Osc + qh * 4096;
#pragma unroll
        for (int mi = 0; mi < 4; ++mi)
#pragma unroll
            for (int ct = 0; ct < 4; ++ct)
                *(f32x4*)(dst + (mi * 4 + ct) * 256 + lane * 4) = o[mi][ct];
    }
    __syncthreads();

    if (kh == 0) {
        const float* src = Osc + qh * 4096;
#pragma unroll
        for (int mi = 0; mi < 4; ++mi)
#pragma unroll
            for (int ct = 0; ct < 4; ++ct)
                o[mi][ct] += *(const f32x4*)(src + (mi * 4 + ct) * 256 + lane * 4);
#pragma unroll
        for (int mi = 0; mi < 4; ++mi)
#pragma unroll
            for (int r = 0; r < 4; ++r) {
                const int qrow = mi * 16 + quad * 4 + r;
                const float l = Lred[(qh * 2) * 64 + qrow] + Lred[(qh * 2 + 1) * 64 + qrow];
                const float inv = 1.0f / l;
                bf16* orow = att + (size_t)(b * 2048 + q0 + qh * 64 + qrow) * 1024 + h * 64 + l16;
#pragma unroll
                for (int ct = 0; ct < 4; ++ct)
                    orow[ct * 16] = (bf16)(o[mi][ct][r] * inv);
            }
    }
}

// ---------------- launch ----------------

extern "C" void kernel_launch(void* const* d_in, const int* in_sizes, int n_in,
                              void* d_out, int out_size, void* d_ws, size_t ws_size,
                              hipStream_t stream) {
    (void)in_sizes; (void)n_in; (void)out_size; (void)ws_size;
    const float* x  = (const float*)d_in[0];
    const float* Wq = (const float*)d_in[1];
    const float* Wk = (const float*)d_in[2];
    const float* Wv = (const float*)d_in[3];
    const float* Wo = (const float*)d_in[4];

    char* ws = (char*)d_ws;
    bf16* xb    = (bf16*)(ws);                             // 8 MB  [4096][1024]
    bf16* att   = xb;                                      // alias: xb dead after QKV GEMM
    bf16* WqkvT = (bf16*)(ws + (size_t)8  * 1024 * 1024);  // 6 MB [3072][1024]
    bf16* WoT   = (bf16*)(ws + (size_t)14 * 1024 * 1024);  // 2 MB [1024][1024]
    bf16* QKV   = (bf16*)(ws + (size_t)16 * 1024 * 1024);  // 24 MB [4096][3072] (V region unused)
    bf16* VT    = (bf16*)(ws + (size_t)40 * 1024 * 1024);  // 8 MB [1024][4096]
    // total 48 MB

    // x->bf16 (z=4) + all 4 weight transposes (z=0..3); Wq pre-scaled
    prep<<<dim3(32, 32, 5), 256, 0, stream>>>(x, Wq, Wk, Wv, Wo, xb, WqkvT, WoT);

    // QKV = xb @ [Wq|Wk|Wv] : M=4096 N=3072 K=1024; 768 blocks, 1D grid with
    // XCD-rectangle swizzle (8 rows x 12 cols per XCD)
    gemm_bt<false><<<768, 256, 0, stream>>>(
        xb, WqkvT, QKV, 4096, 3072, 1024, VT);

    // attention -> att[bs][hc]; grid (bh, qt) so XCD = bh%8 (L2-local K/V)
    flash_attn<<<dim3(32, 16), 256, 0, stream>>>(QKV, VT, att);

    // out = att @ Wo : M=4096 N=1024 K=1024; 512 blocks, 1D grid with
    // XCD-rectangle swizzle (16 rows x 4 cols per XCD)
    gemm_tm2<<<512, 256, 0, stream>>>(
        att, WoT, (float*)d_out, 4096, 1024, 1024);
}

// Round 9
// 175.220 us; speedup vs baseline: 1.0021x; 1.0021x over previous
//
#include <hip/hip_runtime.h>
#include <hip/hip_bf16.h>
#include <stdint.h>
#include <stddef.h>

// B=2, S=2048, D=1024, H=16, C=64
typedef __bf16 bf16;
typedef __bf16 bf16x4 __attribute__((ext_vector_type(4)));
typedef __bf16 bf16x8 __attribute__((ext_vector_type(8)));
typedef float f32x4 __attribute__((ext_vector_type(4)));

#define DEV __device__ __forceinline__

// async global->LDS, 16B per lane; LDS dest is wave-uniform base + lane*16
DEV void async16(const bf16* g, bf16* l) {
    __builtin_amdgcn_global_load_lds(
        (const __attribute__((address_space(1))) void*)g,
        (__attribute__((address_space(3))) void*)l,
        16, 0, 0);
}

// pack two f32 -> two bf16 (truncation) in ONE v_perm_b32.
// Truncation bias cancels in P/l since l is computed from the same packed P.
DEV uint32_t pktrunc(float lo, float hi) {
    return __builtin_amdgcn_perm(__builtin_bit_cast(uint32_t, hi),
                                 __builtin_bit_cast(uint32_t, lo), 0x07060302u);
}

// ---------------- prep: x->bf16 convert (z=4) + 4 weight transposes (z=0..3) --

__global__ void prep(const float* __restrict__ x,
                     const float* __restrict__ Wq, const float* __restrict__ Wk,
                     const float* __restrict__ Wv, const float* __restrict__ Wo,
                     bf16* __restrict__ xb, bf16* __restrict__ WqkvT,
                     bf16* __restrict__ WoT) {
    __shared__ float t[32][33];
    if (blockIdx.z == 4) {
        const int bid = blockIdx.y * 32 + blockIdx.x;
#pragma unroll
        for (int i = 0; i < 4; ++i) {
            const int idx = ((bid * 4 + i) * 256 + threadIdx.x) * 4;
            const float4 v = *(const float4*)(x + idx);
            bf16 o4[4] = {(bf16)v.x, (bf16)v.y, (bf16)v.z, (bf16)v.w};
            *(uint2*)(xb + idx) = *(const uint2*)o4;
        }
        return;
    }
    const float* src;
    bf16* dst;
    float scale = 1.0f;
    switch (blockIdx.z) {
        case 0: src = Wq; dst = WqkvT; scale = 0.125f * 1.4426950408889634f; break;
        case 1: src = Wk; dst = WqkvT + 1024 * 1024; break;
        case 2: src = Wv; dst = WqkvT + 2 * 1024 * 1024; break;
        default: src = Wo; dst = WoT; break;
    }
    const int c0 = blockIdx.x * 32, r0 = blockIdx.y * 32;
    const int tx = threadIdx.x & 31, ty = threadIdx.x >> 5;  // 32x8
#pragma unroll
    for (int i = 0; i < 32; i += 8)
        t[ty + i][tx] = src[(size_t)(r0 + ty + i) * 1024 + c0 + tx];
    __syncthreads();
#pragma unroll
    for (int i = 0; i < 32; i += 8)
        dst[(size_t)(c0 + ty + i) * 1024 + r0 + tx] = (bf16)(t[tx][ty + i] * scale);
}

// ---------------- GEMM 8-phase (T3+T4+T2+T5): 256x256 tile, BK=32 ----------
// C[m][n] = sum_k A[m][k]*BT[n][k], K=1024 fixed. n0>=2048 tiles stored
// transposed to VTout[n-2048][m]. 512 thr = 8 waves (2m x 4n), per-wave
// output 128x64. LDS: 4-deep ring of 32KB buffers (A 256x32 + B 256x32).
// Loads for tile t+2 issued during tile t (buffer last read t-2: race-free).
// Counted vmcnt(4) ONLY at tile boundary (t+1's 4 loads guaranteed landed;
// never drain to 0 in-loop). Raw s_barrier per phase (no vmcnt drain).
// T2 swizzle: read chunk' = quad ^ ((l16>>1)&3) (8-way -> 2-way = free);
// staged via inverse-swizzled global SOURCE, LDS dest linear (rule 21).

__global__ __launch_bounds__(512, 2) void gemm_bt8(
    const bf16* __restrict__ A, const bf16* __restrict__ BT, bf16* __restrict__ C,
    bf16* __restrict__ VTout) {
    __shared__ __attribute__((aligned(16))) char smem[131072];  // 4 x 32KB ring
    const int tid = threadIdx.x;
    const int wid = tid >> 6, lane = tid & 63;
    const int quad = lane >> 4, l16 = lane & 15;
    const int wm = wid >> 2, wn = wid & 3;         // 2 x 4 waves
    const int m0 = (blockIdx.x & 15) * 256;        // 16 m-tiles
    const int n0 = (blockIdx.x >> 4) * 256;        // 12 n-tiles

    // staging geometry: thread -> (row = tid>>2, chunk = tid&3), 16B each;
    // source chunk inverse-swizzled so linear LDS + swizzled reads compose.
    const int srow = tid >> 2;                               // 0..127
    const int chsw = (tid & 3) ^ ((srow >> 1) & 3);
    const bf16* agA1 = A + (size_t)(m0 + srow) * 1024 + chsw * 8;
    const bf16* agA2 = A + (size_t)(m0 + 128 + srow) * 1024 + chsw * 8;
    const bf16* bgB1 = BT + (size_t)(n0 + srow) * 1024 + chsw * 8;
    const bf16* bgB2 = BT + (size_t)(n0 + 128 + srow) * 1024 + chsw * 8;

    // read-side swizzled chunk and row bases (element offsets)
    const int chq = quad ^ ((l16 >> 1) & 3);
    const int rbA = (wm * 128 + l16) * 32 + chq * 8;  // + mi*512
    const int rbB = (wn * 64 + l16) * 32 + chq * 8;   // + ni*512

    f32x4 acc[8][4];
#pragma unroll
    for (int i = 0; i < 8; ++i)
#pragma unroll
        for (int j = 0; j < 4; ++j) acc[i][j] = (f32x4){0.f, 0.f, 0.f, 0.f};

#define STAGE_A8(ts, bufp) do { \
    async16(agA1 + (size_t)(ts) * 32, (bf16*)(bufp) + wid * 512); \
    async16(agA2 + (size_t)(ts) * 32, (bf16*)(bufp) + 4096 + wid * 512); } while (0)
#define STAGE_B8(ts, bufp) do { \
    async16(bgB1 + (size_t)(ts) * 32, (bf16*)(bufp) + wid * 512); \
    async16(bgB2 + (size_t)(ts) * 32, (bf16*)(bufp) + 4096 + wid * 512); } while (0)

    // prologue: stage tiles 0,1 (8 loads); wait for tile 0 (oldest 4)
    STAGE_A8(0, smem);
    STAGE_B8(0, smem + 16384);
    STAGE_A8(1, smem + 32768);
    STAGE_B8(1, smem + 32768 + 16384);
    asm volatile("s_waitcnt vmcnt(4)" ::: "memory");
    __builtin_amdgcn_s_barrier();

    for (int t = 0; t < 32; ++t) {
        const char* bufc = smem + (size_t)(t & 3) * 32768;
        char* bufp = smem + (size_t)((t + 2) & 3) * 32768;
        const bf16* Ab = (const bf16*)bufc;
        const bf16* Bb = (const bf16*)(bufc + 16384);
        const int tsrc = (t + 2) & 31;  // ghost tiles wrap to k=0 (dead bufs)

        // ---- phase 0: B frags + A frags mi0-3; stage next A ----
        bf16x8 bfr[4], afr[4];
#pragma unroll
        for (int ni = 0; ni < 4; ++ni)
            bfr[ni] = *(const bf16x8*)(Bb + rbB + ni * 512);
#pragma unroll
        for (int mi = 0; mi < 4; ++mi)
            afr[mi] = *(const bf16x8*)(Ab + rbA + mi * 512);
        STAGE_A8(tsrc, bufp);
        __builtin_amdgcn_s_barrier();
        __builtin_amdgcn_s_setprio(1);
#pragma unroll
        for (int mi = 0; mi < 4; ++mi)
#pragma unroll
            for (int ni = 0; ni < 4; ++ni)
                acc[mi][ni] = __builtin_amdgcn_mfma_f32_16x16x32_bf16(
                    afr[mi], bfr[ni], acc[mi][ni], 0, 0, 0);
        __builtin_amdgcn_s_setprio(0);
        __builtin_amdgcn_s_barrier();

        // ---- phase 1: A frags mi4-7; stage next B ----
        bf16x8 afr2[4];
#pragma unroll
        for (int mi = 0; mi < 4; ++mi)
            afr2[mi] = *(const bf16x8*)(Ab + rbA + (mi + 4) * 512);
        STAGE_B8(tsrc, bufp + 16384);
        __builtin_amdgcn_s_barrier();
        __builtin_amdgcn_s_setprio(1);
#pragma unroll
        for (int mi = 0; mi < 4; ++mi)
#pragma unroll
            for (int ni = 0; ni < 4; ++ni)
                acc[mi + 4][ni] = __builtin_amdgcn_mfma_f32_16x16x32_bf16(
                    afr2[mi], bfr[ni], acc[mi + 4][ni], 0, 0, 0);
        __builtin_amdgcn_s_setprio(0);
        // tile boundary: t+1's 4 loads are the oldest of the 8 outstanding
        asm volatile("s_waitcnt vmcnt(4)" ::: "memory");
        __builtin_amdgcn_s_barrier();
        __builtin_amdgcn_sched_barrier(0);
    }
#undef STAGE_A8
#undef STAGE_B8

    if (n0 >= 2048) {
        // V tiles: store transposed VT[n-2048][m], 4 consecutive m as 8B
#pragma unroll
        for (int mi = 0; mi < 8; ++mi)
#pragma unroll
            for (int ni = 0; ni < 4; ++ni) {
                bf16 pk[4] = {(bf16)acc[mi][ni][0], (bf16)acc[mi][ni][1],
                              (bf16)acc[mi][ni][2], (bf16)acc[mi][ni][3]};
                *(uint2*)&VTout[(size_t)(n0 - 2048 + wn * 64 + ni * 16 + l16) * 4096 +
                                (m0 + wm * 128 + mi * 16 + quad * 4)] = *(const uint2*)pk;
            }
        return;
    }
#pragma unroll
    for (int mi = 0; mi < 8; ++mi)
#pragma unroll
        for (int ni = 0; ni < 4; ++ni)
#pragma unroll
            for (int r = 0; r < 4; ++r)
                C[(size_t)(m0 + wm * 128 + mi * 16 + quad * 4 + r) * 3072 +
                  (n0 + wn * 64 + ni * 16 + l16)] = (bf16)acc[mi][ni][r];
}

// ---------------- GEMM (TM=2): 64x128 tile, fp32 out --------------------

__global__ __launch_bounds__(256, 4) void gemm_tm2(
    const bf16* __restrict__ A, const bf16* __restrict__ BT, float* __restrict__ C,
    int M, int N, int K) {
    __shared__ __attribute__((aligned(16))) bf16 As[2 * 64 * 32];
    __shared__ __attribute__((aligned(16))) bf16 Bs[2 * 128 * 32];
    const int tid = threadIdx.x;
    const int wid = tid >> 6;
    const int lane = tid & 63;
    const int quad = lane >> 4;
    const int l16 = lane & 15;
    const int wm = wid >> 1, wn = wid & 1;

    // 512 blocks: XCD = orig%8 owns 16 rows x 4 cols
    const int orig = blockIdx.x;
    const int xcd = orig & 7, pos = orig >> 3;          // pos in [0,64)
    const int row = (xcd >> 1) * 16 + (pos & 15);       // [0,64)
    const int col = (xcd & 1) * 4 + (pos >> 4);         // [0,8)
    const int m0 = row * 64, n0 = col * 128;

    const int srowA = wid * 16 + (lane >> 2);
    const int srowB = wid * 32 + (lane >> 2);
    const int skcol = (lane & 3) * 8;
    const bf16* ag = A + (size_t)(m0 + srowA) * K + skcol;
    const bf16* bg = BT + (size_t)(n0 + srowB) * K + skcol;

    f32x4 acc[2][4];
#pragma unroll
    for (int i = 0; i < 2; ++i)
#pragma unroll
        for (int j = 0; j < 4; ++j) acc[i][j] = (f32x4){0.f, 0.f, 0.f, 0.f};

    for (int k0 = 0; k0 < K; k0 += 64) {
#pragma unroll
        for (int p = 0; p < 2; ++p) {
            async16(ag + k0 + p * 32, &As[p * 2048 + (wid * 16) * 32]);
            async16(bg + k0 + p * 32, &Bs[p * 4096 + (wid * 32) * 32]);
            async16(bg + (size_t)16 * K + k0 + p * 32, &Bs[p * 4096 + (wid * 32 + 16) * 32]);
        }
        __syncthreads();

#pragma unroll
        for (int ks = 0; ks < 2; ++ks) {
            bf16x8 af[2], bfr[4];
#pragma unroll
            for (int mi = 0; mi < 2; ++mi)
                af[mi] = *(const bf16x8*)&As[ks * 2048 + (wm * 32 + mi * 16 + l16) * 32 + quad * 8];
#pragma unroll
            for (int ni = 0; ni < 4; ++ni)
                bfr[ni] = *(const bf16x8*)&Bs[ks * 4096 + (wn * 64 + ni * 16 + l16) * 32 + quad * 8];
#pragma unroll
            for (int mi = 0; mi < 2; ++mi)
#pragma unroll
                for (int ni = 0; ni < 4; ++ni)
                    acc[mi][ni] = __builtin_amdgcn_mfma_f32_16x16x32_bf16(
                        af[mi], bfr[ni], acc[mi][ni], 0, 0, 0);
        }
        __syncthreads();
    }

#pragma unroll
    for (int mi = 0; mi < 2; ++mi)
#pragma unroll
        for (int ni = 0; ni < 4; ++ni)
#pragma unroll
            for (int r = 0; r < 4; ++r)
                C[(size_t)(m0 + wm * 32 + mi * 16 + quad * 4 + r) * N +
                  (n0 + wn * 64 + ni * 16 + l16)] = acc[mi][ni][r];
}

// ---------------- flash attention (v16 = v11 EXACT + T5 setprio) ----------
// 45.8us measured x3. Do not restructure without a fully derived schedule.

__global__ __launch_bounds__(256, 2) void flash_attn(
    const bf16* __restrict__ QKV, const bf16* __restrict__ VT, bf16* __restrict__ att) {
    constexpr int LDK = 72;   // Ks stride: frag-read banks 4*(l16+quad) uniform
    constexpr int LDV = 136;  // Vs stride: b64 reads 2-way (free), writes 8-phase
    __shared__ __attribute__((aligned(16))) char smem[36864];
    bf16* Ks = (bf16*)smem;                // [128][72]  = 18432 B
    bf16* Vs = (bf16*)(smem + 18432);      // [64][136]  = 17408 B -> 35840
    float* Osc = (float*)smem;             // epilogue alias: 2 regions x 16 KB
    float* Lred = (float*)(smem + 32768);  // [4][64] floats

    const int tid = threadIdx.x, wid = tid >> 6, lane = tid & 63;
    const int quad = lane >> 4, l16 = lane & 15;
    const int qh = wid >> 1, kh = wid & 1;
    const int bh = blockIdx.x, qt = blockIdx.y;   // XCD = bh % 8 (L2-local K/V)
    const int b = bh >> 4, h = bh & 15;
    const int q0 = qt * 128;

    // ---- Q B-frags (resident): B[k=quad*8+j][n=l16] = Q[q][c] ----
    bf16x8 qf[4][2];
    {
        const bf16* qbase = QKV + (size_t)(b * 2048 + q0 + qh * 64 + l16) * 3072 + h * 64 + quad * 8;
#pragma unroll
        for (int mi = 0; mi < 4; ++mi)
#pragma unroll
            for (int ks = 0; ks < 2; ++ks)
                qf[mi][ks] = *(const bf16x8*)(qbase + (size_t)mi * 16 * 3072 + ks * 32);
    }

    // staging geometry (coalesced): K 128 rows x 128 B, V 64 rows x 256 B
    const int krow = tid >> 3, kcol = (tid & 7) * 8;   // 32 rows/pass, 4 passes
    const int vrow = tid >> 4, vcol = (tid & 15) * 8;  // 16 rows/pass, 4 passes
    const bf16* kg = QKV + (size_t)(b * 2048 + krow) * 3072 + 1024 + h * 64 + kcol;
    const bf16* vg = VT + (size_t)(h * 64 + vrow) * 4096 + b * 2048 + vcol;

    bf16x8 kr[4], vr[4];
#pragma unroll
    for (int p = 0; p < 4; ++p) {
        kr[p] = *(const bf16x8*)(kg + (size_t)(32 * p) * 3072);
        vr[p] = *(const bf16x8*)(vg + (size_t)(16 * p) * 4096);
    }

    const bf16 one = (bf16)1.0f;
    const bf16x8 onesf = (bf16x8){one, one, one, one, one, one, one, one};

    f32x4 o[4][4];
    f32x4 ls[4];
#pragma unroll
    for (int mi = 0; mi < 4; ++mi) {
        ls[mi] = (f32x4){0.f, 0.f, 0.f, 0.f};
#pragma unroll
        for (int ct = 0; ct < 4; ++ct) o[mi][ct] = (f32x4){0.f, 0.f, 0.f, 0.f};
    }

    for (int it = 0; it < 16; ++it) {
        // ---- stage prefetched regs -> LDS ----
#pragma unroll
        for (int p = 0; p < 4; ++p) {
            *(bf16x8*)&Ks[(32 * p + krow) * LDK + kcol] = kr[p];
            *(bf16x8*)&Vs[(16 * p + vrow) * LDV + vcol] = vr[p];
        }
        __syncthreads();

        // ---- prefetch next big-iter (hidden behind compute phase) ----
        if (it < 15) {
            const size_t ko = (size_t)(it + 1) * 128;
#pragma unroll
            for (int p = 0; p < 4; ++p) {
                kr[p] = *(const bf16x8*)(kg + (ko + 32 * p) * 3072);
                vr[p] = *(const bf16x8*)(vg + (size_t)(16 * p) * 4096 + ko);
            }
        }

        // ---- compute: wave's 64 keys as 2 pairs of 16-key groups ----
#pragma unroll
        for (int pr = 0; pr < 2; ++pr) {
            const int kb = kh * 64 + pr * 32;  // pair base (rel key)
            const bf16x8 kfA0 = *(const bf16x8*)&Ks[(kb + l16) * LDK + quad * 8];
            const bf16x8 kfA1 = *(const bf16x8*)&Ks[(kb + l16) * LDK + 32 + quad * 8];
            const bf16x8 kfB0 = *(const bf16x8*)&Ks[(kb + 16 + l16) * LDK + quad * 8];
            const bf16x8 kfB1 = *(const bf16x8*)&Ks[(kb + 16 + l16) * LDK + 32 + quad * 8];
            bf16x8 vf[4];
#pragma unroll
            for (int ct = 0; ct < 4; ++ct) {
                const bf16x4 lo = *(const bf16x4*)&Vs[(ct * 16 + l16) * LDV + kb + quad * 4];
                const bf16x4 hi = *(const bf16x4*)&Vs[(ct * 16 + l16) * LDV + kb + 16 + quad * 4];
                vf[ct] = (bf16x8){lo[0], lo[1], lo[2], lo[3], hi[0], hi[1], hi[2], hi[3]};
            }
            __builtin_amdgcn_s_setprio(1);
#pragma unroll
            for (int mi = 0; mi < 4; ++mi) {
                f32x4 sA = (f32x4){0.f, 0.f, 0.f, 0.f};
                f32x4 sB = (f32x4){0.f, 0.f, 0.f, 0.f};
                sA = __builtin_amdgcn_mfma_f32_16x16x32_bf16(kfA0, qf[mi][0], sA, 0, 0, 0);
                sA = __builtin_amdgcn_mfma_f32_16x16x32_bf16(kfA1, qf[mi][1], sA, 0, 0, 0);
                sB = __builtin_amdgcn_mfma_f32_16x16x32_bf16(kfB0, qf[mi][0], sB, 0, 0, 0);
                sB = __builtin_amdgcn_mfma_f32_16x16x32_bf16(kfB1, qf[mi][1], sB, 0, 0, 0);

                const float pa0 = __builtin_amdgcn_exp2f(sA[0]);
                const float pa1 = __builtin_amdgcn_exp2f(sA[1]);
                const float pa2 = __builtin_amdgcn_exp2f(sA[2]);
                const float pa3 = __builtin_amdgcn_exp2f(sA[3]);
                const float pb0 = __builtin_amdgcn_exp2f(sB[0]);
                const float pb1 = __builtin_amdgcn_exp2f(sB[1]);
                const float pb2 = __builtin_amdgcn_exp2f(sB[2]);
                const float pb3 = __builtin_amdgcn_exp2f(sB[3]);

                // P A-frag via truncation pack (4 v_perm); lane = P[q=l16][j0..7]
                union { uint32_t u[4]; bf16x8 v; } pu;
                pu.u[0] = pktrunc(pa0, pa1);
                pu.u[1] = pktrunc(pa2, pa3);
                pu.u[2] = pktrunc(pb0, pb1);
                pu.u[3] = pktrunc(pb2, pb3);
                const bf16x8 pf = pu.v;
#pragma unroll
                for (int ct = 0; ct < 4; ++ct)
                    o[mi][ct] = __builtin_amdgcn_mfma_f32_16x16x32_bf16(pf, vf[ct], o[mi][ct], 0, 0, 0);
                // l-sum on the matrix pipe: D[q][*] = sum_k pf (all cols equal)
                ls[mi] = __builtin_amdgcn_mfma_f32_16x16x32_bf16(pf, onesf, ls[mi], 0, 0, 0);
            }
            __builtin_amdgcn_s_setprio(0);
        }
        __syncthreads();
    }

    // ---- epilogue: publish l (already row-summed, q = mi*16+quad*4+r), ----
    // ---- cross-wave O reduce ----
    if (l16 == 0) {
#pragma unroll
        for (int mi = 0; mi < 4; ++mi)
#pragma unroll
            for (int r = 0; r < 4; ++r)
                Lred[wid * 64 + mi * 16 + quad * 4 + r] = ls[mi][r];
    }
    if (kh == 1) {
        float* dst = Osc + qh * 4096;
#pragma unroll
        for (int mi = 0; mi < 4; ++mi)
#pragma unroll
            for (int ct = 0; ct < 4; ++ct)
                *(f32x4*)(dst + (mi * 4 + ct) * 256 + lane * 4) = o[mi][ct];
    }
    __syncthreads();

    if (kh == 0) {
        const float* src = Osc + qh * 4096;
#pragma unroll
        for (int mi = 0; mi < 4; ++mi)
#pragma unroll
            for (int ct = 0; ct < 4; ++ct)
                o[mi][ct] += *(const f32x4*)(src + (mi * 4 + ct) * 256 + lane * 4);
#pragma unroll
        for (int mi = 0; mi < 4; ++mi)
#pragma unroll
            for (int r = 0; r < 4; ++r) {
                const int qrow = mi * 16 + quad * 4 + r;
                const float l = Lred[(qh * 2) * 64 + qrow] + Lred[(qh * 2 + 1) * 64 + qrow];
                const float inv = 1.0f / l;
                bf16* orow = att + (size_t)(b * 2048 + q0 + qh * 64 + qrow) * 1024 + h * 64 + l16;
#pragma unroll
                for (int ct = 0; ct < 4; ++ct)
                    orow[ct * 16] = (bf16)(o[mi][ct][r] * inv);
            }
    }
}

// ---------------- launch ----------------

extern "C" void kernel_launch(void* const* d_in, const int* in_sizes, int n_in,
                              void* d_out, int out_size, void* d_ws, size_t ws_size,
                              hipStream_t stream) {
    (void)in_sizes; (void)n_in; (void)out_size; (void)ws_size;
    const float* x  = (const float*)d_in[0];
    const float* Wq = (const float*)d_in[1];
    const float* Wk = (const float*)d_in[2];
    const float* Wv = (const float*)d_in[3];
    const float* Wo = (const float*)d_in[4];

    char* ws = (char*)d_ws;
    bf16* xb    = (bf16*)(ws);                             // 8 MB  [4096][1024]
    bf16* att   = xb;                                      // alias: xb dead after QKV GEMM
    bf16* WqkvT = (bf16*)(ws + (size_t)8  * 1024 * 1024);  // 6 MB [3072][1024]
    bf16* WoT   = (bf16*)(ws + (size_t)14 * 1024 * 1024);  // 2 MB [1024][1024]
    bf16* QKV   = (bf16*)(ws + (size_t)16 * 1024 * 1024);  // 24 MB [4096][3072] (V region unused)
    bf16* VT    = (bf16*)(ws + (size_t)40 * 1024 * 1024);  // 8 MB [1024][4096]
    // total 48 MB

    // x->bf16 (z=4) + all 4 weight transposes (z=0..3); Wq pre-scaled
    prep<<<dim3(32, 32, 5), 256, 0, stream>>>(x, Wq, Wk, Wv, Wo, xb, WqkvT, WoT);

    // QKV = xb @ [Wq|Wk|Wv] : M=4096 N=3072 K=1024; 8-phase 256^2 kernel,
    // 192 blocks x 512 thr; V tiles transposed straight to VT
    gemm_bt8<<<16 * 12, 512, 0, stream>>>(xb, WqkvT, QKV, VT);

    // attention -> att[bs][hc]; grid (bh, qt) so XCD = bh%8 (L2-local K/V)
    flash_attn<<<dim3(32, 16), 256, 0, stream>>>(QKV, VT, att);

    // out = att @ Wo : M=4096 N=1024 K=1024; 512 blocks, XCD-rect swizzle
    gemm_tm2<<<512, 256, 0, stream>>>(
        att, WoT, (float*)d_out, 4096, 1024, 1024);
}